// Round 12
// baseline (1649.033 us; speedup 1.0000x reference)
//
#include <hip/hip_runtime.h>
#include <math.h>

// Problem dims (fixed by the reference)
#define BN    32          // batch
#define TN    512         // TFs
#define GN    2000        // genes
#define PPGN  10          // peaks per gene
#define PN    (GN*PPGN)   // 20000 peaks
#define EN    64000       // edges
#define NOUTN 10          // output channels
#define PQN   (PN/4)      // 5000 p-quads (float4 granules)

#define TCH   8           // number of t-chunks
#define TPC   (TN/TCH)    // 64 t per chunk
#define BQ    8           // batch groups (new: 8 groups of 4)
#define BPH   (BN/BQ)     // 4 batches per thread
#define TW    4           // t-batch: W quads preloaded to registers

// probe geometry (EXACTLY R10's r8_nt: BPH=8, BQ=4)
#define PBQ   4
#define PBPH  8
#define REP   6

typedef float float4v __attribute__((ext_vector_type(4)));

// ---------- DISCRIMINATING PROBE (single, so FETCH_SIZE is visible) ----------
// R10 left ambiguity: r8_nt's 6.7 TB/s was DEMAND-side; its HBM-side rate was
// never observed (no FETCH). If memory-side L3 serves nt re-reads, true HBM
// read ceiling may be ~4.5 TB/s = what k_perpeak gets. This probe tops the
// dispatch table -> its FETCH_SIZE/dur gives the HBM-side read rate for the
// exact k_perpeak x-pattern. FETCH ~7.8GB @~1.2ms => reads can do 6.5+;
// FETCH/dur ~4.5 TB/s => k_perpeak is AT the read roofline.
__global__ __launch_bounds__(256)
void k_probe_r8_nt(const float* __restrict__ x, float* __restrict__ po) {
    int ptile = blockIdx.x;             // 0..19
    int bq    = blockIdx.y;             // 0..3
    int tc    = blockIdx.z;             // 0..7
    int pq    = ptile * 256 + threadIdx.x;
    if (pq >= PQN) return;
    int b0 = bq * PBPH;
    int t0 = tc * TPC;
    const float4v* xp = (const float4v*)x + ((size_t)b0 * TN + t0) * PQN + pq;
    float4v acc = {0.f, 0.f, 0.f, 0.f};
    for (int r = 0; r < REP; ++r) {
#pragma unroll 2
        for (int t = 0; t < TPC; ++t) {
#pragma unroll
            for (int j = 0; j < PBPH; ++j)
                acc += __builtin_nontemporal_load(xp + ((size_t)j * TN + t) * PQN);
        }
    }
    size_t gid = ((size_t)((blockIdx.z * 4 + blockIdx.y) * 20 + blockIdx.x)) * 256
               + threadIdx.x;
    po[gid] = acc.x + acc.y + acc.z + acc.w;
}

// ---------- Stage 1: max-occupancy variant ----------
// Only axis never isolated: occupancy. Probes ran at 71% occ (32 waves/CU);
// k_perpeak ~10-20. This version: BPH=4 + TW=4 (acc 16 + wv 16 VGPR),
// __launch_bounds__(256,8) forces <=64 VGPR -> 8 waves/SIMD; grid
// 20x8x8=1280 blocks = 5 blocks/CU = 20 waves/CU.
__global__ __launch_bounds__(256, 8)
void k_perpeak(const float* __restrict__ x,
               const float* __restrict__ W_sub,
               float* __restrict__ partial) {
    int ptile = blockIdx.x;             // 0..19 (fast axis)
    int bq    = blockIdx.y;             // 0..7
    int tc    = blockIdx.z;             // 0..7
    int pq    = ptile * 256 + threadIdx.x;
    if (pq >= PQN) return;              // last ptile: 136/256 active
    int b0 = bq * BPH;
    int t0 = tc * TPC;

    const float4v* xp = (const float4v*)x + ((size_t)b0 * TN + t0) * PQN + pq;
    const float4v* wp = (const float4v*)W_sub + (size_t)t0 * PQN + pq;

    float4v acc[BPH];
#pragma unroll
    for (int j = 0; j < BPH; ++j) acc[j] = (float4v){0.f, 0.f, 0.f, 0.f};

#pragma unroll 1
    for (int t8 = 0; t8 < TPC; t8 += TW) {
        float4v wv[TW];
#pragma unroll
        for (int u = 0; u < TW; ++u)
            wv[u] = wp[(size_t)(t8 + u) * PQN];
#pragma unroll
        for (int j = 0; j < BPH; ++j) {
#pragma unroll
            for (int u = 0; u < TW; ++u) {
                float4v xv = __builtin_nontemporal_load(
                    xp + ((size_t)j * TN + t8 + u) * PQN);
                acc[j] = xv * wv[u] + acc[j];
            }
        }
    }

    float4v* pp = (float4v*)partial + ((size_t)tc * BN + b0) * PQN + pq;
#pragma unroll
    for (int j = 0; j < BPH; ++j)
        __builtin_nontemporal_store(acc[j], pp + (size_t)j * PQN);
}

// Stage 2: h[b,g] = relu(b_sub[g] + sum_tc sum_{k<10} partial[tc][b][g*10+k])
__global__ void k_h(const float* __restrict__ partial,
                    const float* __restrict__ b_sub,
                    float* __restrict__ h) {
    int idx = blockIdx.x * blockDim.x + threadIdx.x;
    if (idx >= BN * GN) return;
    int g = idx % GN, b = idx / GN;
    float s = b_sub[g];
    for (int tc = 0; tc < TCH; ++tc) {
        const float* pp = partial + ((size_t)tc * BN + b) * PN + g * PPGN;
#pragma unroll
        for (int k = 0; k < PPGN; ++k) s += pp[k];
    }
    h[idx] = fmaxf(s, 0.0f);
}

__global__ void k_deg(const int* __restrict__ col, float* __restrict__ deg) {
    int e = blockIdx.x * blockDim.x + threadIdx.x;
    if (e < EN) atomicAdd(&deg[col[e]], 1.0f);
}

__global__ void k_dinv(const float* __restrict__ deg, float* __restrict__ dinv) {
    int g = blockIdx.x * blockDim.x + threadIdx.x;
    if (g < GN) {
        float d = deg[g];
        dinv[g] = (d > 0.0f) ? (1.0f / sqrtf(d)) : 0.0f;
    }
}

__global__ __launch_bounds__(256)
void k_s(const int* __restrict__ row, const int* __restrict__ col,
         const float* __restrict__ dinv, const float* __restrict__ h,
         float* __restrict__ s) {
    __shared__ float s_lds[GN];
    int b = blockIdx.x;
    for (int g = threadIdx.x; g < GN; g += 256) s_lds[g] = 0.0f;
    __syncthreads();
    const float* hb = h + (size_t)b * GN;
    for (int e = threadIdx.x; e < EN; e += 256) {
        int r = row[e], c = col[e];
        float nrm = dinv[r] * dinv[c];
        atomicAdd(&s_lds[c], nrm * hb[r]);
    }
    __syncthreads();
    for (int g = threadIdx.x; g < GN; g += 256)
        s[(size_t)b * GN + g] = s_lds[g];
}

__global__ void k_out(const float* __restrict__ s,
                      const float* __restrict__ W_gcn,
                      const float* __restrict__ b_gcn,
                      const float* __restrict__ W_out,
                      const float* __restrict__ b_out,
                      float* __restrict__ out) {
    int b = blockIdx.x / NOUTN;
    int n = blockIdx.x % NOUTN;
    int lane = threadIdx.x;

    float w0 = W_gcn[0], w1 = W_gcn[1];
    float c0 = b_gcn[0], c1 = b_gcn[1];

    float acc = 0.0f;
    for (int g = lane; g < GN; g += 64) {
        float sv = s[(size_t)b * GN + g];
        float g0 = fmaxf(fmaf(sv, w0, c0), 0.0f);
        float g1 = fmaxf(fmaf(sv, w1, c1), 0.0f);
        const float* wo = &W_out[(size_t)n * (GN * 2) + 2 * g];
        acc = fmaf(g0, wo[0], acc);
        acc = fmaf(g1, wo[1], acc);
    }
#pragma unroll
    for (int off = 32; off > 0; off >>= 1)
        acc += __shfl_down(acc, off);
    if (lane == 0) out[b * NOUTN + n] = acc + b_out[n];
}

extern "C" void kernel_launch(void* const* d_in, const int* in_sizes, int n_in,
                              void* d_out, int out_size, void* d_ws, size_t ws_size,
                              hipStream_t stream) {
    const float* x         = (const float*)d_in[0];
    const int*   edge_index= (const int*)  d_in[1];
    const float* W_sub     = (const float*)d_in[2];
    const float* b_sub     = (const float*)d_in[3];
    const float* W_gcn     = (const float*)d_in[4];
    const float* b_gcn     = (const float*)d_in[5];
    const float* W_out     = (const float*)d_in[6];
    const float* b_out     = (const float*)d_in[7];
    float* out = (float*)d_out;

    char* ws = (char*)d_ws;
    // partial: TCH*BN*PN floats = 8*32*20000*4B = 20,480,000 B
    float* partial = (float*)(ws);
    float* h       = (float*)(ws + 20480000);       // B*G floats = 256,000 B
    float* deg     = (float*)(ws + 20736000);       // G   floats =   8,000 B
    float* dinv    = (float*)(ws + 20744000);       // G   floats =   8,000 B
    float* s       = (float*)(ws + 20752000);       // B*G floats = 256,000 B
    float* po3     = (float*)(ws + 24000000);       // probe out: 655,360 B

    const int* row = edge_index;        // edge_index[0,:]
    const int* col = edge_index + EN;   // edge_index[1,:]

    // ---- single probe (discriminating measurement: FETCH_SIZE visible) ----
    dim3 grid_probe(20, PBQ, TCH);
    k_probe_r8_nt<<<grid_probe, 256, 0, stream>>>(x, po3);

    // ---- pipeline ----
    hipMemsetAsync(deg, 0, GN * sizeof(float), stream);
    dim3 grid_pp(20, BQ, TCH);   // 1280 blocks
    k_perpeak<<<grid_pp, 256, 0, stream>>>(x, W_sub, partial);
    k_h      <<<((BN * GN) + 255) / 256, 256, 0, stream>>>(partial, b_sub, h);
    k_deg    <<<(EN + 255) / 256,        256, 0, stream>>>(col, deg);
    k_dinv   <<<(GN + 255) / 256,        256, 0, stream>>>(deg, dinv);
    k_s      <<<BN, 256, 0, stream>>>(row, col, dinv, h, s);
    k_out    <<<BN * NOUTN, 64, 0, stream>>>(s, W_gcn, b_gcn, W_out, b_out, out);
}

// Round 13
// 415.946 us; speedup vs baseline: 3.9645x; 3.9645x over previous
//
#include <hip/hip_runtime.h>
#include <math.h>

// Problem dims (fixed by the reference)
#define BN    32          // batch
#define TN    512         // TFs
#define GN    2000        // genes
#define PPGN  10          // peaks per gene
#define PN    (GN*PPGN)   // 20000 peaks
#define EN    64000       // edges
#define NOUTN 10          // output channels
#define PQN   (PN/4)      // 5000 p-quads (float4 granules)

#define TCH   8           // number of t-chunks
#define TPC   (TN/TCH)    // 64 t per chunk
#define BQ    4           // batch quarters
#define BPH   (BN/BQ)     // 8 batches per thread

typedef float float4v __attribute__((ext_vector_type(4)));

// Stage 1 — UNCHANGED from R8 (proven 359.5 total; ~330us, 4.4 TB/s).
// R12 probe verdict: r8_nt's 6.57 TB/s demand was ~50% cache-served
// (FETCH=3.88GB of 7.86 demanded); single-pass HBM reads converge to
// ~4.5 TB/s across 9 configs -> kpp is at that cap. Remaining recoverable
// time is the downstream tail, not kpp.
__global__ __launch_bounds__(256)
void k_perpeak(const float* __restrict__ x,
               const float* __restrict__ W_sub,
               float* __restrict__ partial) {
    int ptile = blockIdx.x;             // 0..19 (fast axis)
    int bq    = blockIdx.y;             // 0..3
    int tc    = blockIdx.z;             // 0..7
    int pq    = ptile * 256 + threadIdx.x;
    if (pq >= PQN) return;              // last ptile: 136/256 active
    int b0 = bq * BPH;
    int t0 = tc * TPC;

    const float4v* xp = (const float4v*)x + ((size_t)b0 * TN + t0) * PQN + pq;
    const float4v* wp = (const float4v*)W_sub + (size_t)t0 * PQN + pq;

    float4v acc[BPH];
#pragma unroll
    for (int j = 0; j < BPH; ++j) acc[j] = (float4v){0.f, 0.f, 0.f, 0.f};

#pragma unroll 2
    for (int t = 0; t < TPC; ++t) {
        float4v wv = wp[(size_t)t * PQN];
#pragma unroll
        for (int j = 0; j < BPH; ++j) {
            float4v xv = __builtin_nontemporal_load(xp + ((size_t)j * TN + t) * PQN);
            acc[j] = xv * wv + acc[j];
        }
    }

    float4v* pp = (float4v*)partial + ((size_t)tc * BN + b0) * PQN + pq;
#pragma unroll
    for (int j = 0; j < BPH; ++j)
        __builtin_nontemporal_store(acc[j], pp + (size_t)j * PQN);
}

// Stage 2: h[b,g] = relu(b_sub[g] + sum_tc sum_{k<10} partial[tc][b][g*10+k])
// Kept separate: 20MB partial reduction wants the wide 250-block shape.
__global__ void k_h(const float* __restrict__ partial,
                    const float* __restrict__ b_sub,
                    float* __restrict__ h) {
    int idx = blockIdx.x * blockDim.x + threadIdx.x;
    if (idx >= BN * GN) return;
    int g = idx % GN, b = idx / GN;
    float s = b_sub[g];
    for (int tc = 0; tc < TCH; ++tc) {
        const float* pp = partial + ((size_t)tc * BN + b) * PN + g * PPGN;
#pragma unroll
        for (int k = 0; k < PPGN; ++k) s += pp[k];
    }
    h[idx] = fmaxf(s, 0.0f);
}

// Stage 3+4 fused (tail collapse): per-batch block computes deg, dinv, s, out
// entirely in LDS. Replaces k_deg/k_dinv/k_s/k_out + the deg memset: 4
// launches + memset + serialization gaps -> 1 launch. Edges (512KB) read
// twice per block, L3-shared across the 32 blocks. LDS = 24KB.
__global__ __launch_bounds__(256)
void k_epi(const int* __restrict__ row, const int* __restrict__ col,
           const float* __restrict__ h,
           const float* __restrict__ W_gcn, const float* __restrict__ b_gcn,
           const float* __restrict__ W_out, const float* __restrict__ b_out,
           float* __restrict__ out) {
    __shared__ float dinv_l[GN];
    __shared__ float h_l[GN];
    __shared__ float s_l[GN];
    int b = blockIdx.x;

    for (int g = threadIdx.x; g < GN; g += 256) {
        dinv_l[g] = 0.0f;
        s_l[g]    = 0.0f;
        h_l[g]    = h[(size_t)b * GN + g];
    }
    __syncthreads();

    // deg (LDS atomics)
    for (int e = threadIdx.x; e < EN; e += 256)
        atomicAdd(&dinv_l[col[e]], 1.0f);
    __syncthreads();

    // dinv = deg^-1/2 in place (1/sqrtf for exact parity with prior rounds)
    for (int g = threadIdx.x; g < GN; g += 256) {
        float d = dinv_l[g];
        dinv_l[g] = (d > 0.0f) ? (1.0f / sqrtf(d)) : 0.0f;
    }
    __syncthreads();

    // s[g] = sum_{e: col==g} dinv[row]*dinv[col]*h[row]
    for (int e = threadIdx.x; e < EN; e += 256) {
        int r = row[e], c = col[e];
        atomicAdd(&s_l[c], dinv_l[r] * dinv_l[c] * h_l[r]);
    }
    __syncthreads();

    // out[b,n] = b_out[n] + sum_g sum_c relu(W_gcn[c]*s[g]+b_gcn[c]) * W_out[n,2g+c]
    int wave = threadIdx.x >> 6;
    int lane = threadIdx.x & 63;
    float w0 = W_gcn[0], w1 = W_gcn[1];
    float c0 = b_gcn[0], c1 = b_gcn[1];
    for (int n = wave; n < NOUTN; n += 4) {
        float acc = 0.0f;
        for (int g = lane; g < GN; g += 64) {
            float sv = s_l[g];
            float g0 = fmaxf(fmaf(sv, w0, c0), 0.0f);
            float g1 = fmaxf(fmaf(sv, w1, c1), 0.0f);
            const float* wo = &W_out[(size_t)n * (GN * 2) + 2 * g];
            acc = fmaf(g0, wo[0], acc);
            acc = fmaf(g1, wo[1], acc);
        }
#pragma unroll
        for (int off = 32; off > 0; off >>= 1)
            acc += __shfl_down(acc, off);
        if (lane == 0) out[b * NOUTN + n] = acc + b_out[n];
    }
}

extern "C" void kernel_launch(void* const* d_in, const int* in_sizes, int n_in,
                              void* d_out, int out_size, void* d_ws, size_t ws_size,
                              hipStream_t stream) {
    const float* x         = (const float*)d_in[0];
    const int*   edge_index= (const int*)  d_in[1];
    const float* W_sub     = (const float*)d_in[2];
    const float* b_sub     = (const float*)d_in[3];
    const float* W_gcn     = (const float*)d_in[4];
    const float* b_gcn     = (const float*)d_in[5];
    const float* W_out     = (const float*)d_in[6];
    const float* b_out     = (const float*)d_in[7];
    float* out = (float*)d_out;

    char* ws = (char*)d_ws;
    // partial: TCH*BN*PN floats = 8*32*20000*4B = 20,480,000 B
    float* partial = (float*)(ws);
    float* h       = (float*)(ws + 20480000);       // B*G floats = 256,000 B

    const int* row = edge_index;        // edge_index[0,:]
    const int* col = edge_index + EN;   // edge_index[1,:]

    dim3 grid_pp(20, BQ, TCH);   // x = p-tile (fast), y = b-quarter, z = t-chunk
    k_perpeak<<<grid_pp, 256, 0, stream>>>(x, W_sub, partial);
    k_h      <<<((BN * GN) + 255) / 256, 256, 0, stream>>>(partial, b_sub, h);
    k_epi    <<<BN, 256, 0, stream>>>(row, col, h, W_gcn, b_gcn, W_out, b_out, out);
}

// Round 14
// 358.782 us; speedup vs baseline: 4.5962x; 1.1593x over previous
//
#include <hip/hip_runtime.h>
#include <math.h>

// Problem dims (fixed by the reference)
#define BN    32          // batch
#define TN    512         // TFs
#define GN    2000        // genes
#define PPGN  10          // peaks per gene
#define PN    (GN*PPGN)   // 20000 peaks
#define EN    64000       // edges
#define NOUTN 10          // output channels
#define PQN   (PN/4)      // 5000 p-quads (float4 granules)

#define TCH   8           // number of t-chunks
#define TPC   (TN/TCH)    // 64 t per chunk
#define BQ    4           // batch quarters
#define BPH   (BN/BQ)     // 8 batches per thread

typedef float float4v __attribute__((ext_vector_type(4)));

// Stage 1 — R8-exact (best measured: 359.5us total).
// Evidence trail: 9 configs (scalar/vector, nt/cached, 160-1280 blocks,
// 8-20 waves/CU, strided/linear/slab) converge at 4.4-4.6 TB/s single-pass
// HBM reads; R12 probe FETCH showed demand-side 6.5 TB/s was ~50% L3-served
// (HBM-side 3.2). x is read-once (1.31GB, no reuse) -> kpp floor ~320us.
// R13 proved the tail is parallelism-bound, not launch-bound (fusion lost
// 56us). This IS the measured roofline configuration.
__global__ __launch_bounds__(256)
void k_perpeak(const float* __restrict__ x,
               const float* __restrict__ W_sub,
               float* __restrict__ partial) {
    int ptile = blockIdx.x;             // 0..19 (fast axis)
    int bq    = blockIdx.y;             // 0..3
    int tc    = blockIdx.z;             // 0..7
    int pq    = ptile * 256 + threadIdx.x;
    if (pq >= PQN) return;              // last ptile: 136/256 active
    int b0 = bq * BPH;
    int t0 = tc * TPC;

    const float4v* xp = (const float4v*)x + ((size_t)b0 * TN + t0) * PQN + pq;
    const float4v* wp = (const float4v*)W_sub + (size_t)t0 * PQN + pq;

    float4v acc[BPH];
#pragma unroll
    for (int j = 0; j < BPH; ++j) acc[j] = (float4v){0.f, 0.f, 0.f, 0.f};

#pragma unroll 2
    for (int t = 0; t < TPC; ++t) {
        float4v wv = wp[(size_t)t * PQN];
#pragma unroll
        for (int j = 0; j < BPH; ++j) {
            float4v xv = __builtin_nontemporal_load(xp + ((size_t)j * TN + t) * PQN);
            acc[j] = xv * wv + acc[j];
        }
    }

    float4v* pp = (float4v*)partial + ((size_t)tc * BN + b0) * PQN + pq;
#pragma unroll
    for (int j = 0; j < BPH; ++j)
        __builtin_nontemporal_store(acc[j], pp + (size_t)j * PQN);
}

// Stage 2: h[b,g] = relu(b_sub[g] + sum_tc sum_{k<10} partial[tc][b][g*10+k])
__global__ void k_h(const float* __restrict__ partial,
                    const float* __restrict__ b_sub,
                    float* __restrict__ h) {
    int idx = blockIdx.x * blockDim.x + threadIdx.x;
    if (idx >= BN * GN) return;
    int g = idx % GN, b = idx / GN;
    float s = b_sub[g];
    for (int tc = 0; tc < TCH; ++tc) {
        const float* pp = partial + ((size_t)tc * BN + b) * PN + g * PPGN;
#pragma unroll
        for (int k = 0; k < PPGN; ++k) s += pp[k];
    }
    h[idx] = fmaxf(s, 0.0f);
}

// Stage 3a: degree of target nodes (col)
__global__ void k_deg(const int* __restrict__ col, float* __restrict__ deg) {
    int e = blockIdx.x * blockDim.x + threadIdx.x;
    if (e < EN) atomicAdd(&deg[col[e]], 1.0f);
}

// Stage 3b: dinv = deg^-1/2 (0 where deg == 0)
__global__ void k_dinv(const float* __restrict__ deg, float* __restrict__ dinv) {
    int g = blockIdx.x * blockDim.x + threadIdx.x;
    if (g < GN) {
        float d = deg[g];
        dinv[g] = (d > 0.0f) ? (1.0f / sqrtf(d)) : 0.0f;
    }
}

// Stage 3c: s[b,g] = sum_{e: col[e]==g} dinv[row]*dinv[col] * h[b,row]
// One block per batch; accumulate in LDS (8KB) with LDS atomics, single
// non-atomic writeback.
__global__ __launch_bounds__(256)
void k_s(const int* __restrict__ row, const int* __restrict__ col,
         const float* __restrict__ dinv, const float* __restrict__ h,
         float* __restrict__ s) {
    __shared__ float s_lds[GN];
    int b = blockIdx.x;
    for (int g = threadIdx.x; g < GN; g += 256) s_lds[g] = 0.0f;
    __syncthreads();
    const float* hb = h + (size_t)b * GN;
    for (int e = threadIdx.x; e < EN; e += 256) {
        int r = row[e], c = col[e];
        float nrm = dinv[r] * dinv[c];
        atomicAdd(&s_lds[c], nrm * hb[r]);
    }
    __syncthreads();
    for (int g = threadIdx.x; g < GN; g += 256)
        s[(size_t)b * GN + g] = s_lds[g];
}

// Stage 4: out[b,n] = sum_g sum_c relu(W_gcn[c]*s[b,g]+b_gcn[c]) * W_out[n,2g+c] + b_out[n]
// One wave (64 threads) per (b,n).
__global__ void k_out(const float* __restrict__ s,
                      const float* __restrict__ W_gcn,
                      const float* __restrict__ b_gcn,
                      const float* __restrict__ W_out,
                      const float* __restrict__ b_out,
                      float* __restrict__ out) {
    int b = blockIdx.x / NOUTN;
    int n = blockIdx.x % NOUTN;
    int lane = threadIdx.x;

    float w0 = W_gcn[0], w1 = W_gcn[1];
    float c0 = b_gcn[0], c1 = b_gcn[1];

    float acc = 0.0f;
    for (int g = lane; g < GN; g += 64) {
        float sv = s[(size_t)b * GN + g];
        float g0 = fmaxf(fmaf(sv, w0, c0), 0.0f);
        float g1 = fmaxf(fmaf(sv, w1, c1), 0.0f);
        const float* wo = &W_out[(size_t)n * (GN * 2) + 2 * g];
        acc = fmaf(g0, wo[0], acc);
        acc = fmaf(g1, wo[1], acc);
    }
#pragma unroll
    for (int off = 32; off > 0; off >>= 1)
        acc += __shfl_down(acc, off);
    if (lane == 0) out[b * NOUTN + n] = acc + b_out[n];
}

extern "C" void kernel_launch(void* const* d_in, const int* in_sizes, int n_in,
                              void* d_out, int out_size, void* d_ws, size_t ws_size,
                              hipStream_t stream) {
    const float* x         = (const float*)d_in[0];
    const int*   edge_index= (const int*)  d_in[1];
    const float* W_sub     = (const float*)d_in[2];
    const float* b_sub     = (const float*)d_in[3];
    const float* W_gcn     = (const float*)d_in[4];
    const float* b_gcn     = (const float*)d_in[5];
    const float* W_out     = (const float*)d_in[6];
    const float* b_out     = (const float*)d_in[7];
    float* out = (float*)d_out;

    char* ws = (char*)d_ws;
    // partial: TCH*BN*PN floats = 8*32*20000*4B = 20,480,000 B
    float* partial = (float*)(ws);
    float* h       = (float*)(ws + 20480000);       // B*G floats = 256,000 B
    float* deg     = (float*)(ws + 20736000);       // G   floats =   8,000 B
    float* dinv    = (float*)(ws + 20744000);       // G   floats =   8,000 B
    float* s       = (float*)(ws + 20752000);       // B*G floats = 256,000 B

    const int* row = edge_index;        // edge_index[0,:]
    const int* col = edge_index + EN;   // edge_index[1,:]

    // deg is atomically accumulated -> zero it every call (graph-capture legal)
    hipMemsetAsync(deg, 0, GN * sizeof(float), stream);

    dim3 grid_pp(20, BQ, TCH);   // x = p-tile (fast), y = b-quarter, z = t-chunk
    k_perpeak<<<grid_pp, 256, 0, stream>>>(x, W_sub, partial);
    k_h      <<<((BN * GN) + 255) / 256, 256, 0, stream>>>(partial, b_sub, h);
    k_deg    <<<(EN + 255) / 256,        256, 0, stream>>>(col, deg);
    k_dinv   <<<(GN + 255) / 256,        256, 0, stream>>>(deg, dinv);
    k_s      <<<BN, 256, 0, stream>>>(row, col, dinv, h, s);
    k_out    <<<BN * NOUTN, 64, 0, stream>>>(s, W_gcn, b_gcn, W_out, b_out, out);
}